// Round 10
// baseline (80.455 us; speedup 1.0000x reference)
//
#include <hip/hip_runtime.h>
#include <hip/hip_bf16.h>
#include <math.h>

typedef __attribute__((ext_vector_type(8))) short short8;
typedef __attribute__((ext_vector_type(4))) float floatx4;

#define MAGIC 0x5EEDBEEFu
// ws layout:
//   flags:      8 classes x 32 u32 at offset 0 (only [g*32+u], u<24 used)
//   per class g (bid&7): region at (1+g)MB:
//     wredT: 8192 f32 ([sel][K][h]), wmaT at +512KB: 64*2048 bf16 (B-fragment layout)
#define WS_CLASS(g) ((size_t)(1 + (g)) << 20)
#define WMA_OFF (512u << 10)

__device__ __forceinline__ float eluf(float v) {
  return v > 0.f ? v : __expf(v) - 1.f;
}

__device__ __forceinline__ unsigned short f2bf(float f) {
  __hip_bfloat16 h = __float2bfloat16(f);
  return *reinterpret_cast<unsigned short*>(&h);
}

// ============ single mono kernel ============
// All blocks: x load -> [producers: per-class weight prep] -> pooled + rcp ->
// spin on class flags -> MFMA einsum + DI/DD + MLP tail (R7-identical).
// Class g = bid&7 replicates wredT/wmaT so producers and consumers share an XCD L2.
__global__ __launch_bounds__(1024, 8) void mono_kernel(
    const float* __restrict__ x,
    const float* __restrict__ wm_di,
    const float* __restrict__ wm_ndi,
    const float* __restrict__ wm_dd,
    const float* __restrict__ b_di, const float* __restrict__ b_ndi,
    const float* __restrict__ b_dd,
    const float* __restrict__ fcw_di, const float* __restrict__ fcb_di,
    const float* __restrict__ fcw_ndi, const float* __restrict__ fcb_ndi,
    const float* __restrict__ fcw_dd, const float* __restrict__ fcb_dd,
    const float* __restrict__ fc1_w, const float* __restrict__ fc1_b,
    const float* __restrict__ fc2_w, const float* __restrict__ fc2_b,
    char* __restrict__ ws,
    float* __restrict__ out) {
  __shared__ float xs[2][256];
  __shared__ __align__(16) union {
    unsigned short ldsA[2][2][2048];  // [plane hi/lo][row][k] bf16 (16 KB)
    float sm[64 * 65];                // prep transpose buffer (16.6 KB)
  } sh;
  __shared__ float pxs[2][64], pds[2][64];
  __shared__ float hp[16][4][2][16];  // [kh][n][row][col] einsum partials
  __shared__ float hh[3][2][64];
  __shared__ float emb_s[2][144];
  __shared__ float f1v_s[2][48];

  const int t = threadIdx.x;
  const int bid = blockIdx.x;
  const int b0 = bid * 2;
  const int g = bid & 7, uu = bid >> 3;

  unsigned* __restrict__ flags = (unsigned*)ws;
  float* __restrict__ wredT_c = (float*)(ws + WS_CLASS(g));
  __hip_bfloat16* __restrict__ wmaT_c = (__hip_bfloat16*)(ws + WS_CLASS(g) + WMA_OFF);

  // ---- x load: 2 rows ----
  if (t < 512) xs[t >> 8][t & 255] = x[(b0 + (t >> 8)) * 256 + (t & 255)];
  __syncthreads();

  // ---- producers: first 24 blocks of each class build the class's weight copies ----
  if (uu < 24) {
#pragma unroll 1
    for (int q = 0; q < 8; ++q) {
      const int hu = uu * 8 + q;  // 0..191
      const float* __restrict__ w = (hu < 64)  ? wm_di + hu * 4096
                                  : (hu < 128) ? wm_dd + (hu - 64) * 4096
                                               : wm_ndi + (hu - 128) * 4096;
#pragma unroll
      for (int i = 0; i < 4; ++i) {
        const int e = i * 1024 + t;
        sh.sm[(e >> 6) * 65 + (e & 63)] = w[e];
      }
      __syncthreads();
      if (hu < 128) {
        // wredT[sel][K][h] = sum_I (w[I][K] - w[K][I]); 16 threads per K
        const int sel = hu >> 6, h = hu & 63;
        const int K = t >> 4, part = t & 15;
        float a = 0.f;
#pragma unroll
        for (int ii = 0; ii < 4; ++ii) {
          const int I = part * 4 + ii;
          a += sh.sm[I * 65 + K] - sh.sm[K * 65 + I];
        }
        a += __shfl_xor(a, 1, 64);
        a += __shfl_xor(a, 2, 64);
        a += __shfl_xor(a, 4, 64);
        a += __shfl_xor(a, 8, 64);
        if (part == 0) wredT_c[sel * 4096 + K * 64 + h] = a;
      } else {
        // wmaT fold: element ((n*64+kstep)*64+lane)*8+j, h=n*16+(lane&15),
        // k=kstep*32+(lane>>4)*8+j, I=k>>5, J=(I+1+(k&31))&63, dup cols zeroed
        const int h = hu - 128;
        if (t < 256) {
          const int kstep = t >> 2, kc = t & 3;
          const int lane2 = kc * 16 + (h & 15);
          const int n = h >> 4;
          short8 sv;
#pragma unroll
          for (int j = 0; j < 8; ++j) {
            const int k = kstep * 32 + kc * 8 + j;
            const int I = k >> 5, tt2 = k & 31;
            const int J = (I + 1 + tt2) & 63;
            float v = 0.f;
            if (!(tt2 == 31 && I >= 32))
              v = 0.0625f * (sh.sm[I * 65 + J] - sh.sm[J * 65 + I]);
            sv[j] = (short)f2bf(v);
          }
          *(short8*)(wmaT_c + (((n * 64 + kstep) * 64 + lane2) << 3)) = sv;
        }
      }
      __syncthreads();  // sm reads done before next stage / rcp overwrite
    }
    __threadfence();  // publish class region before flag
    if (t == 0)
      __hip_atomic_store(&flags[g * 32 + uu], MAGIC, __ATOMIC_RELEASE,
                         __HIP_MEMORY_SCOPE_AGENT);
  }

  // ---- pooled x + telescoped pooled diff (2 waves) ----
  if (t < 128) {
    const int r = t >> 6, m = t & 63;
    const float* __restrict__ xr = xs[r];
    const int b4 = 4 * m;
    pxs[r][m] = 0.25f * (xr[b4] + xr[b4 + 1] + xr[b4 + 2] + xr[b4 + 3]);
    const int i3 = min(b4 + 4, 255), i4 = min(b4 + 5, 255);
    const float smv = 0.2f * (xr[b4 + 1] + xr[b4 + 2] + xr[b4 + 3] + xr[i3] + xr[i4]);
    float prev = __shfl_up(smv, 1, 64);
    if (m == 0) prev = xr[0];
    pds[r][m] = 0.25f * (smv - prev);
  }

  // ---- antisym rcp rectangle -> LDS bf16 hi/lo: 4096 entries, 4/thread ----
  // paired fractions (exact algebra): 8 rcp per entry.
#pragma unroll 1
  for (int i = 0; i < 4; ++i) {
    const int cc = t + i * 1024;
    const int r = cc >> 11, e = cc & 2047;
    const int I = e >> 5;
    const int J = (I + 1 + (e & 31)) & 63;
    const float4 xiv = *(const float4*)&xs[r][I << 2];
    const float4 xjv = *(const float4*)&xs[r][J << 2];
    const float P01 = 2.f * xjv.x * xjv.y + (xjv.x + xjv.y) * 1e-5f;
    const float P23 = 2.f * xjv.z * xjv.w + (xjv.z + xjv.w) * 1e-5f;
    const float ya[4] = {xiv.x, xiv.y, xiv.z, xiv.w};
    float s = 0.f;
#pragma unroll
    for (int a = 0; a < 4; ++a) {
      const float y = ya[a];
      const float u2 = y + 1e-5f;
      const float G = 2.f * y * u2;
      const float D0 = (xjv.x + u2) * (xjv.y + u2);
      const float D1 = (xjv.z + u2) * (xjv.w + u2);
      s += (P01 - G) * __builtin_amdgcn_rcpf(D0);
      s += (P23 - G) * __builtin_amdgcn_rcpf(D1);
    }
    const unsigned short hi = f2bf(s);
    union { unsigned int ub; float f; } hv; hv.ub = ((unsigned int)hi) << 16;
    sh.ldsA[0][r][e] = hi;
    sh.ldsA[1][r][e] = f2bf(s - hv.f);
  }

  // ---- wait for this class's 24 producer flags (bounded; poison != MAGIC) ----
  {
    const int lane = t & 63;
    if (t < 64) {
      int iters = 0;
      bool ok;
      do {
        unsigned f = MAGIC;
        if (lane < 24)
          f = __hip_atomic_load(&flags[g * 32 + lane], __ATOMIC_ACQUIRE,
                                __HIP_MEMORY_SCOPE_AGENT);
        ok = __all(f == MAGIC);
      } while (!ok && ++iters < (1 << 22));
    }
    __syncthreads();
  }

  // ---- MFMA einsum: wave kh owns K-slice of 128; n-outer to keep regs low ----
  {
    const int kh = t >> 6, lane = t & 63;
    const int arow = lane & 1;
    const int kofs = kh * 128 + ((lane >> 4) << 3);
    const short* __restrict__ wmaT = (const short*)wmaT_c;
#pragma unroll
    for (int n = 0; n < 4; ++n) {
      floatx4 acc = {0.f, 0.f, 0.f, 0.f};
#pragma unroll
      for (int s = 0; s < 4; ++s) {
        const int kk = kofs + s * 32;
        const short8 ah = *(const short8*)&sh.ldsA[0][arow][kk];
        const short8 al = *(const short8*)&sh.ldsA[1][arow][kk];
        const int kstep = kh * 4 + s;
        const short8 bv = *(const short8*)(wmaT + (((n * 64 + kstep) * 64 + lane) << 3));
        acc = __builtin_amdgcn_mfma_f32_16x16x32_bf16(ah, bv, acc, 0, 0, 0);
        acc = __builtin_amdgcn_mfma_f32_16x16x32_bf16(al, bv, acc, 0, 0, 0);
      }
      // C/D layout (m89): col=lane&15, row=(lane>>4)*4+reg -> rows 0,1 in lanes 0..15
      if (lane < 16) {
        hp[kh][n][0][lane] = acc[0];
        hp[kh][n][1][lane] = acc[1];
      }
    }
  }

  // ---- DI/DD separable projections (same barrier interval) ----
  if (t < 128) {
    const int r = t >> 6, h = t & 63;
    float adi = b_di[h], add_ = b_dd[h];
#pragma unroll 8
    for (int K = 0; K < 64; ++K) {
      adi += pxs[r][K] * wredT_c[K * 64 + h];
      add_ += pds[r][K] * wredT_c[4096 + K * 64 + h];
    }
    hh[0][r][h] = eluf(adi);
    hh[2][r][h] = eluf(add_);
  }
  __syncthreads();

  // ---- combine K-slice partials -> NDI heads ----
  if (t < 128) {
    const int row = t >> 6, h = t & 63;
    const int n = h >> 4, c = h & 15;
    float v = b_ndi[h];
#pragma unroll
    for (int kh = 0; kh < 16; ++kh) v += hp[kh][n][row][c];
    hh[1][row][h] = eluf(v);
  }
  __syncthreads();

  // ---- per-picker fc: HEAD(64) -> EMB(48) ----
  if (t < 2 * 144) {
    const int r = t / 144;
    const int k = t - r * 144;
    const int pick = k / 48;
    const int e = k - pick * 48;
    const float* __restrict__ fw = (pick == 0) ? fcw_di : (pick == 1) ? fcw_ndi : fcw_dd;
    const float* __restrict__ fb = (pick == 0) ? fcb_di : (pick == 1) ? fcb_ndi : fcb_dd;
    float a = fb[e];
#pragma unroll 8
    for (int hq = 0; hq < 64; ++hq) a += hh[pick][r][hq] * fw[e * 64 + hq];
    emb_s[r][k] = eluf(a);
  }
  __syncthreads();

  // ---- fc1: 144 -> 48, elu ----
  if (t < 2 * 48) {
    const int r = t / 48, o = t - (t / 48) * 48;
    float a = fc1_b[o];
#pragma unroll 8
    for (int k = 0; k < 144; ++k) a += emb_s[r][k] * fc1_w[o * 144 + k];
    f1v_s[r][o] = eluf(a);
  }
  __syncthreads();

  // ---- fc2: 48 -> 20 ----
  if (t < 2 * 20) {
    const int r = t / 20, o = t - (t / 20) * 20;
    float a = fc2_b[o];
#pragma unroll
    for (int j = 0; j < 48; ++j) a += f1v_s[r][j] * fc2_w[o * 48 + j];
    out[(b0 + r) * 20 + o] = a;
  }
}

extern "C" void kernel_launch(void* const* d_in, const int* in_sizes, int n_in,
                              void* d_out, int out_size, void* d_ws, size_t ws_size,
                              hipStream_t stream) {
  const float* x       = (const float*)d_in[0];
  const float* wm_di   = (const float*)d_in[1];
  const float* b_di    = (const float*)d_in[2];
  const float* fcw_di  = (const float*)d_in[3];
  const float* fcb_di  = (const float*)d_in[4];
  const float* wm_ndi  = (const float*)d_in[5];
  const float* b_ndi   = (const float*)d_in[6];
  const float* fcw_ndi = (const float*)d_in[7];
  const float* fcb_ndi = (const float*)d_in[8];
  const float* wm_dd   = (const float*)d_in[9];
  const float* b_dd    = (const float*)d_in[10];
  const float* fcw_dd  = (const float*)d_in[11];
  const float* fcb_dd  = (const float*)d_in[12];
  const float* fc1_w   = (const float*)d_in[13];
  const float* fc1_b   = (const float*)d_in[14];
  const float* fc2_w   = (const float*)d_in[15];
  const float* fc2_b   = (const float*)d_in[16];
  float* out = (float*)d_out;
  char* ws = (char*)d_ws;

  mono_kernel<<<512, 1024, 0, stream>>>(
      x, wm_di, wm_ndi, wm_dd, b_di, b_ndi, b_dd,
      fcw_di, fcb_di, fcw_ndi, fcb_ndi, fcw_dd, fcb_dd,
      fc1_w, fc1_b, fc2_w, fc2_b, ws, out);
}

// Round 11
// 27.812 us; speedup vs baseline: 2.8928x; 2.8928x over previous
//
#include <hip/hip_runtime.h>
#include <hip/hip_bf16.h>
#include <math.h>

typedef __attribute__((ext_vector_type(8))) short short8;
typedef __attribute__((ext_vector_type(4))) float floatx4;

// ---- workspace layout ----
#define WS_WREDT 0u          // 8192 f32 (32 KB), [sel][K][h]
#define WS_WMAT  (1u << 20)  // 4*64*64*8 bf16 = 256 KB, B-fragment-swizzled

__device__ __forceinline__ float eluf(float v) {
  return v > 0.f ? v : __expf(v) - 1.f;
}

__device__ __forceinline__ unsigned short f2bf(float f) {
  __hip_bfloat16 h = __float2bfloat16(f);
  return *reinterpret_cast<unsigned short*>(&h);
}

// ============ prep ============
// blocks 0..127: wredT[sel][K][h] = colsum-rowsum of wm_di/wm_dd head h (LDS transpose)
// blocks 128..191: per-head wmaT fold into MFMA-B-fragment layout:
//   element ((n*64+kstep)*64+lane)*8+j = bf16(0.0625*(w[h,I,J]-w[h,J,I])),
//   h=n*16+(lane&15), k=kstep*32+(lane>>4)*8+j, I=k>>5, J=(I+1+(k&31))&63,
//   duplicate d=32 columns (k&31==31 && I>=32) zeroed.
__global__ __launch_bounds__(256) void prep_kernel(
    const float* __restrict__ wm_di,
    const float* __restrict__ wm_ndi,
    const float* __restrict__ wm_dd,
    char* __restrict__ ws) {
  __shared__ float sm[64 * 65];
  const int t = threadIdx.x;
  if (blockIdx.x < 128) {
    const int sel = blockIdx.x >> 6, h = blockIdx.x & 63;
    const float* w = (sel ? wm_dd : wm_di) + h * 4096;
#pragma unroll 4
    for (int i = 0; i < 16; ++i) {
      const int e = i * 256 + t;
      sm[(e >> 6) * 65 + (e & 63)] = w[e];
    }
    __syncthreads();
    if (t < 64) {
      float cs = 0.f, rs = 0.f;
#pragma unroll 8
      for (int I = 0; I < 64; ++I) {
        cs += sm[I * 65 + t];
        rs += sm[t * 65 + I];
      }
      ((float*)(ws + WS_WREDT))[sel * 4096 + t * 64 + h] = cs - rs;
    }
  } else {
    const int h = blockIdx.x - 128;  // 0..63
    const float* w = wm_ndi + h * 4096;
#pragma unroll 4
    for (int i = 0; i < 16; ++i) {
      const int e = i * 256 + t;
      sm[(e >> 6) * 65 + (e & 63)] = w[e];
    }
    __syncthreads();
    const int kstep = t >> 2, kc = t & 3;
    const int lane = kc * 16 + (h & 15);
    const int n = h >> 4;
    short8 sv;
#pragma unroll
    for (int j = 0; j < 8; ++j) {
      const int k = kstep * 32 + kc * 8 + j;
      const int I = k >> 5, tt = k & 31;
      const int J = (I + 1 + tt) & 63;
      float v = 0.f;
      if (!(tt == 31 && I >= 32))
        v = 0.0625f * (sm[I * 65 + J] - sm[J * 65 + I]);
      sv[j] = (short)f2bf(v);
    }
    *(short8*)((__hip_bfloat16*)(ws + WS_WMAT) + (((n * 64 + kstep) * 64 + lane) << 3)) = sv;
  }
}

// ============ fused: paired-rcp rectangle -> in-LDS MFMA einsum -> MLP tail ============
// grid 256, 1024 threads (16 waves), 4 batch rows per block
__global__ __launch_bounds__(1024, 8) void fused_kernel(
    const float* __restrict__ x,
    const float* __restrict__ b_di, const float* __restrict__ b_ndi,
    const float* __restrict__ b_dd,
    const float* __restrict__ fcw_di, const float* __restrict__ fcb_di,
    const float* __restrict__ fcw_ndi, const float* __restrict__ fcb_ndi,
    const float* __restrict__ fcw_dd, const float* __restrict__ fcb_dd,
    const float* __restrict__ fc1_w, const float* __restrict__ fc1_b,
    const float* __restrict__ fc2_w, const float* __restrict__ fc2_b,
    const char* __restrict__ ws,
    float* __restrict__ out) {
  __shared__ float xs[4][256];
  __shared__ __align__(16) unsigned short ldsA[2][4][2048];  // [plane hi/lo][row][k] bf16
  __shared__ float pxs[4][64], pds[4][64];
  __shared__ float hp[16][4][4][16];  // [kh][n][row][col] einsum partials
  __shared__ float hh[3][4][64];
  __shared__ float emb_s[4][144];
  __shared__ float f1v_s[4][48];

  const int t = threadIdx.x;
  const int b0 = blockIdx.x * 4;
  const float* __restrict__ wredT = (const float*)(ws + WS_WREDT);  // [sel][K][h]
  const short* __restrict__ wmaT = (const short*)(ws + WS_WMAT);

  // ---- x load: 4 rows x 256 ----
  xs[t >> 8][t & 255] = x[(b0 + (t >> 8)) * 256 + (t & 255)];
  __syncthreads();

  // ---- pooled x + telescoped pooled diff (4 waves) ----
  if (t < 256) {
    const int r = t >> 6, m = t & 63;
    const float* __restrict__ xr = xs[r];
    const int b4 = 4 * m;
    pxs[r][m] = 0.25f * (xr[b4] + xr[b4 + 1] + xr[b4 + 2] + xr[b4 + 3]);
    const int i3 = min(b4 + 4, 255), i4 = min(b4 + 5, 255);
    const float smv = 0.2f * (xr[b4 + 1] + xr[b4 + 2] + xr[b4 + 3] + xr[i3] + xr[i4]);
    float prev = __shfl_up(smv, 1, 64);
    if (m == 0) prev = xr[0];
    pds[r][m] = 0.25f * (smv - prev);
  }

  // ---- antisym rcp rectangle -> LDS bf16 hi/lo: 4 rows x 2048, 8/thread ----
  // paired fractions (exact algebra): 8 rcp per entry.
#pragma unroll 1
  for (int i = 0; i < 8; ++i) {
    const int cc = t + i * 1024;
    const int r = cc >> 11, e = cc & 2047;
    const int I = e >> 5;
    const int J = (I + 1 + (e & 31)) & 63;
    const float4 xiv = *(const float4*)&xs[r][I << 2];
    const float4 xjv = *(const float4*)&xs[r][J << 2];
    const float P01 = 2.f * xjv.x * xjv.y + (xjv.x + xjv.y) * 1e-5f;
    const float P23 = 2.f * xjv.z * xjv.w + (xjv.z + xjv.w) * 1e-5f;
    const float ya[4] = {xiv.x, xiv.y, xiv.z, xiv.w};
    float s = 0.f;
#pragma unroll
    for (int a = 0; a < 4; ++a) {
      const float y = ya[a];
      const float u = y + 1e-5f;
      const float G = 2.f * y * u;
      const float D0 = (xjv.x + u) * (xjv.y + u);
      const float D1 = (xjv.z + u) * (xjv.w + u);
      s += (P01 - G) * __builtin_amdgcn_rcpf(D0);
      s += (P23 - G) * __builtin_amdgcn_rcpf(D1);
    }
    const unsigned short hi = f2bf(s);
    union { unsigned int uu; float f; } hv; hv.uu = ((unsigned int)hi) << 16;
    ldsA[0][r][e] = hi;
    ldsA[1][r][e] = f2bf(s - hv.f);
  }
  __syncthreads();

  // ---- MFMA einsum: wave kh owns K-slice of 128; n-outer to keep regs low ----
  // M rows 0..3 real; A rows 4..15 replicate row (lane&15)&3 (independent MFMA
  // rows -> junk never mixes into rows 0..3; C rows 0..3 live in lanes 0..15).
  {
    const int kh = t >> 6, lane = t & 63;
    const int arow = (lane & 15) & 3;
    const int kofs = kh * 128 + ((lane >> 4) << 3);
#pragma unroll
    for (int n = 0; n < 4; ++n) {
      floatx4 acc = {0.f, 0.f, 0.f, 0.f};
#pragma unroll
      for (int s = 0; s < 4; ++s) {
        const int kk = kofs + s * 32;
        const short8 ah = *(const short8*)&ldsA[0][arow][kk];
        const short8 al = *(const short8*)&ldsA[1][arow][kk];
        const int kstep = kh * 4 + s;
        const short8 bv = *(const short8*)(wmaT + (((n * 64 + kstep) * 64 + lane) << 3));
        acc = __builtin_amdgcn_mfma_f32_16x16x32_bf16(ah, bv, acc, 0, 0, 0);
        acc = __builtin_amdgcn_mfma_f32_16x16x32_bf16(al, bv, acc, 0, 0, 0);
      }
      // C/D layout (m89): col=lane&15, row=(lane>>4)*4+reg -> rows 0..3 = lanes 0..15 regs 0..3
      if (lane < 16) {
        hp[kh][n][0][lane] = acc[0];
        hp[kh][n][1][lane] = acc[1];
        hp[kh][n][2][lane] = acc[2];
        hp[kh][n][3][lane] = acc[3];
      }
    }
  }

  // ---- DI/DD separable projections (same barrier interval) ----
  if (t < 256) {
    const int r = t >> 6, h = t & 63;
    float adi = b_di[h], add_ = b_dd[h];
#pragma unroll 8
    for (int K = 0; K < 64; ++K) {
      adi += pxs[r][K] * wredT[K * 64 + h];
      add_ += pds[r][K] * wredT[4096 + K * 64 + h];
    }
    hh[0][r][h] = eluf(adi);
    hh[2][r][h] = eluf(add_);
  }
  __syncthreads();

  // ---- combine K-slice partials -> NDI heads ----
  if (t < 256) {
    const int row = t >> 6, h = t & 63;
    const int n = h >> 4, c = h & 15;
    float v = b_ndi[h];
#pragma unroll
    for (int kh = 0; kh < 16; ++kh) v += hp[kh][n][row][c];
    hh[1][row][h] = eluf(v);
  }
  __syncthreads();

  // ---- per-picker fc: HEAD(64) -> EMB(48), 4 rows x 144 = 576 threads ----
  if (t < 4 * 144) {
    const int r = t / 144;
    const int k = t - r * 144;
    const int pick = k / 48;
    const int e = k - pick * 48;
    const float* __restrict__ fw = (pick == 0) ? fcw_di : (pick == 1) ? fcw_ndi : fcw_dd;
    const float* __restrict__ fb = (pick == 0) ? fcb_di : (pick == 1) ? fcb_ndi : fcb_dd;
    float a = fb[e];
#pragma unroll 8
    for (int hq = 0; hq < 64; ++hq) a += hh[pick][r][hq] * fw[e * 64 + hq];
    emb_s[r][k] = eluf(a);
  }
  __syncthreads();

  // ---- fc1: 144 -> 48, elu ----
  if (t < 4 * 48) {
    const int r = t / 48, o = t - (t / 48) * 48;
    float a = fc1_b[o];
#pragma unroll 8
    for (int k = 0; k < 144; ++k) a += emb_s[r][k] * fc1_w[o * 144 + k];
    f1v_s[r][o] = eluf(a);
  }
  __syncthreads();

  // ---- fc2: 48 -> 20 ----
  if (t < 4 * 20) {
    const int r = t / 20, o = t - (t / 20) * 20;
    float a = fc2_b[o];
#pragma unroll
    for (int j = 0; j < 48; ++j) a += f1v_s[r][j] * fc2_w[o * 48 + j];
    out[(b0 + r) * 20 + o] = a;
  }
}

extern "C" void kernel_launch(void* const* d_in, const int* in_sizes, int n_in,
                              void* d_out, int out_size, void* d_ws, size_t ws_size,
                              hipStream_t stream) {
  const float* x       = (const float*)d_in[0];
  const float* wm_di   = (const float*)d_in[1];
  const float* b_di    = (const float*)d_in[2];
  const float* fcw_di  = (const float*)d_in[3];
  const float* fcb_di  = (const float*)d_in[4];
  const float* wm_ndi  = (const float*)d_in[5];
  const float* b_ndi   = (const float*)d_in[6];
  const float* fcw_ndi = (const float*)d_in[7];
  const float* fcb_ndi = (const float*)d_in[8];
  const float* wm_dd   = (const float*)d_in[9];
  const float* b_dd    = (const float*)d_in[10];
  const float* fcw_dd  = (const float*)d_in[11];
  const float* fcb_dd  = (const float*)d_in[12];
  const float* fc1_w   = (const float*)d_in[13];
  const float* fc1_b   = (const float*)d_in[14];
  const float* fc2_w   = (const float*)d_in[15];
  const float* fc2_b   = (const float*)d_in[16];
  float* out = (float*)d_out;
  char* ws = (char*)d_ws;

  prep_kernel<<<192, 256, 0, stream>>>(wm_di, wm_ndi, wm_dd, ws);
  fused_kernel<<<256, 1024, 0, stream>>>(
      x, b_di, b_ndi, b_dd,
      fcw_di, fcb_di, fcw_ndi, fcb_ndi, fcw_dd, fcb_dd,
      fc1_w, fc1_b, fc2_w, fc2_b, ws, out);
}